// Round 5
// baseline (143.187 us; speedup 1.0000x reference)
//
#include <hip/hip_runtime.h>

// Problem constants: input [8,16,512,1024] f32, disp [8,1,512,1024] f32
constexpr int B = 8;
constexpr int C = 16;
constexpr int H = 512;
constexpr int W = 1024;
constexpr int W4 = W / 4;   // 256 float4 groups per row

// Native clang vector type — accepted by __builtin_nontemporal_store
// (HIP's float4 is a class and is rejected).
typedef float f32x4 __attribute__((ext_vector_type(4)));

// One thread per (b,h,w4) handling 4 consecutive w positions.
// Horizontal bilinear warp:
//   x  = clip(w + disp, 0, W-1)
//   x0 = floor(x); x1 = min(x0+1, W-1)
//   wl = x1 - x;  wr = x - x0     (both 0 at the right clamp)
// Indices/weights computed once per position, reused across all C=16 channels.
// disp read and output store are 16 B/lane; only the data-dependent gathers
// are scalar dword (L1 absorbs the pl/pr and neighbor-lane overlap).
__global__ __launch_bounds__(256) void warp_bilinear_w4(
    const float* __restrict__ input,
    const float* __restrict__ disp,
    float* __restrict__ out)
{
    const int idx = blockIdx.x * blockDim.x + threadIdx.x;   // over B*H*W4
    if (idx >= B * H * W4) return;

    const int w4 = idx & (W4 - 1);     // W4 = 256 = 2^8
    const int bh = idx >> 8;           // b*H + h
    const int w0 = w4 * 4;

    // disp is [B,1,H,W]: flat position index
    const int pos = bh * W + w0;       // 16B-aligned (w0 % 4 == 0)
    const f32x4 d4 = *reinterpret_cast<const f32x4*>(disp + pos);

    int   x0[4], x1[4];
    float wl[4], wr[4];
#pragma unroll
    for (int k = 0; k < 4; ++k) {
        float x = (float)(w0 + k) + d4[k];
        x = fminf(fmaxf(x, 0.0f), (float)(W - 1));
        const float x0f = floorf(x);
        const float x1f = fminf(x0f + 1.0f, (float)(W - 1));
        x0[k] = (int)x0f;
        x1[k] = (int)x1f;
        wl[k] = x1f - x;
        wr[k] = x - x0f;
    }

    const int b = bh >> 9;             // H = 512 = 2^9
    const int h = bh & (H - 1);
    const int base = (b * C * H + h) * W;   // (b, c=0, h, 0)

#pragma unroll
    for (int c = 0; c < C; ++c) {
        const float* __restrict__ row = input + base + c * (H * W);
        f32x4 o;
        o[0] = wl[0] * row[x0[0]] + wr[0] * row[x1[0]];
        o[1] = wl[1] * row[x0[1]] + wr[1] * row[x1[1]];
        o[2] = wl[2] * row[x0[2]] + wr[2] * row[x1[2]];
        o[3] = wl[3] * row[x0[3]] + wr[3] * row[x1[3]];
        __builtin_nontemporal_store(
            o, reinterpret_cast<f32x4*>(out + base + c * (H * W) + w0));
    }
}

extern "C" void kernel_launch(void* const* d_in, const int* in_sizes, int n_in,
                              void* d_out, int out_size, void* d_ws, size_t ws_size,
                              hipStream_t stream) {
    const float* input = (const float*)d_in[0];
    const float* disp  = (const float*)d_in[1];
    float* out = (float*)d_out;

    const int n = B * H * W4;                  // 1,048,576 threads
    const int block = 256;
    const int grid = (n + block - 1) / block;  // 4096 blocks
    warp_bilinear_w4<<<grid, block, 0, stream>>>(input, disp, out);
}

// Round 6
// 98.813 us; speedup vs baseline: 1.4491x; 1.4491x over previous
//
#include <hip/hip_runtime.h>

// Problem constants: input [8,16,512,1024] f32, disp [8,1,512,1024] f32
constexpr int B = 8;
constexpr int C = 16;
constexpr int H = 512;
constexpr int W = 1024;
constexpr int HW = H * W;
constexpr int THREADS = 512;

typedef float f32x4 __attribute__((ext_vector_type(4)));

// One block per (b,h) row. Stage all C=16 channel rows (64 KB) into LDS with
// coalesced dwordx4 loads, then gather from LDS instead of L1.
//   x  = clip(w + disp, 0, W-1); x0 = floor(x); x1 = min(x0+1, W-1)
//   wl = x1 - x; wr = x - x0   (both exactly 0 when x0 == W-1, so reading
//   from a = min(x0, W-2) and a+1 is always correct AND always in-bounds)
// Gather addresses per lane ~= lane + disp -> ~2 lanes/bank (free, m136);
// row[a], row[a+1] merge into one ds_read2_b32.
__global__ __launch_bounds__(THREADS) void warp_row_lds(
    const float* __restrict__ input,
    const float* __restrict__ disp,
    float* __restrict__ out)
{
    __shared__ float lds[C * W];        // 16 * 1024 * 4 B = 64 KiB

    const int bh = blockIdx.x;          // b*H + h
    const int b  = bh >> 9;             // H = 512
    const int h  = bh & (H - 1);
    const int t  = threadIdx.x;

    const int base0 = b * C * HW + h * W;   // (b, c=0, h, 0); max idx < 2^27

    // ---- Stage: 16 rows x 1024 floats = 4096 float4; 8 per thread ----
#pragma unroll
    for (int i = 0; i < 8; ++i) {
        const int f = t + i * THREADS;      // float4 index in [0, 4096)
        const int c = f >> 8;               // 256 float4 per channel row
        const int q = (f & 255) << 2;       // float offset within row
        const f32x4 v = *reinterpret_cast<const f32x4*>(input + base0 + c * HW + q);
        *reinterpret_cast<f32x4*>(&lds[(c << 10) + q]) = v;
    }

    // ---- Weights for this thread's two positions (overlaps staging latency) ----
    const int p0 = t;
    const int p1 = t + THREADS;
    const float d0 = disp[bh * W + p0];
    const float d1 = disp[bh * W + p1];

    float x  = fminf(fmaxf((float)p0 + d0, 0.0f), (float)(W - 1));
    float x0f = floorf(x);
    const float wl0 = fminf(x0f + 1.0f, (float)(W - 1)) - x;
    const float wr0 = x - x0f;
    const int   a0  = min((int)x0f, W - 2);

    x   = fminf(fmaxf((float)p1 + d1, 0.0f), (float)(W - 1));
    x0f = floorf(x);
    const float wl1 = fminf(x0f + 1.0f, (float)(W - 1)) - x;
    const float wr1 = x - x0f;
    const int   a1  = min((int)x0f, W - 2);

    __syncthreads();

    // ---- Gather from LDS, store coalesced nontemporal ----
#pragma unroll
    for (int c = 0; c < C; ++c) {
        const float* __restrict__ row = &lds[c << 10];
        const float o0 = wl0 * row[a0] + wr0 * row[a0 + 1];
        const float o1 = wl1 * row[a1] + wr1 * row[a1 + 1];
        float* orow = out + base0 + c * HW;
        __builtin_nontemporal_store(o0, orow + p0);
        __builtin_nontemporal_store(o1, orow + p1);
    }
}

extern "C" void kernel_launch(void* const* d_in, const int* in_sizes, int n_in,
                              void* d_out, int out_size, void* d_ws, size_t ws_size,
                              hipStream_t stream) {
    const float* input = (const float*)d_in[0];
    const float* disp  = (const float*)d_in[1];
    float* out = (float*)d_out;

    const int grid = B * H;   // 4096 blocks, one per (b,h) row
    warp_row_lds<<<grid, THREADS, 0, stream>>>(input, disp, out);
}

// Round 7
// 90.348 us; speedup vs baseline: 1.5848x; 1.0937x over previous
//
#include <hip/hip_runtime.h>

// Problem constants: input [8,16,512,1024] f32, disp [8,1,512,1024] f32
constexpr int B = 8;
constexpr int C = 16;
constexpr int H = 512;
constexpr int W = 1024;
constexpr int HW = H * W;
constexpr int THREADS = 1024;   // one thread per w position

typedef float f32x4 __attribute__((ext_vector_type(4)));

// One block per (b,h) row, 1024 threads (1 per w). Stage all C=16 channel
// rows (64 KB) into LDS with coalesced dwordx4 loads, then gather from LDS.
// 64 KB LDS x 1024 threads -> 2 blocks/CU = 32 waves/CU (full wave slots),
// vs R6's 512-thread blocks which left half the wave slots empty (32% occ).
//   x  = clip(w + disp, 0, W-1); x0 = floor(x); x1 = min(x0+1, W-1)
//   wl = x1 - x; wr = x - x0   (both exactly 0 when x0 == W-1, so reading
//   from a = min(x0, W-2) and a+1 is always correct AND always in-bounds)
__global__ __launch_bounds__(THREADS) void warp_row_lds2(
    const float* __restrict__ input,
    const float* __restrict__ disp,
    float* __restrict__ out)
{
    __shared__ float lds[C * W];        // 64 KiB

    const int bh = blockIdx.x;          // b*H + h
    const int b  = bh >> 9;             // H = 512
    const int h  = bh & (H - 1);
    const int t  = threadIdx.x;

    const int base0 = b * C * HW + h * W;   // (b, c=0, h, 0)

    // ---- Stage: 16 rows x 1024 floats = 4096 float4; 4 per thread ----
#pragma unroll
    for (int i = 0; i < 4; ++i) {
        const int f = t + i * THREADS;      // float4 index in [0, 4096)
        const int c = f >> 8;               // 256 float4 per channel row
        const int q = (f & 255) << 2;       // float offset within row
        const f32x4 v = *reinterpret_cast<const f32x4*>(input + base0 + c * HW + q);
        *reinterpret_cast<f32x4*>(&lds[(c << 10) + q]) = v;
    }

    // ---- Weights for this thread's position (overlaps staging latency) ----
    const float d = disp[bh * W + t];
    float x   = fminf(fmaxf((float)t + d, 0.0f), (float)(W - 1));
    float x0f = floorf(x);
    const float wl = fminf(x0f + 1.0f, (float)(W - 1)) - x;
    const float wr = x - x0f;
    const int   a  = min((int)x0f, W - 2);

    __syncthreads();

    // ---- Gather from LDS, store coalesced nontemporal ----
#pragma unroll
    for (int c = 0; c < C; ++c) {
        const float* __restrict__ row = &lds[c << 10];
        const float o = wl * row[a] + wr * row[a + 1];
        __builtin_nontemporal_store(o, out + base0 + c * HW + t);
    }
}

extern "C" void kernel_launch(void* const* d_in, const int* in_sizes, int n_in,
                              void* d_out, int out_size, void* d_ws, size_t ws_size,
                              hipStream_t stream) {
    const float* input = (const float*)d_in[0];
    const float* disp  = (const float*)d_in[1];
    float* out = (float*)d_out;

    const int grid = B * H;   // 4096 blocks, one per (b,h) row
    warp_row_lds2<<<grid, THREADS, 0, stream>>>(input, disp, out);
}

// Round 8
// 85.412 us; speedup vs baseline: 1.6764x; 1.0578x over previous
//
#include <hip/hip_runtime.h>

// Problem constants: input [8,16,512,1024] f32, disp [8,1,512,1024] f32
constexpr int B = 8;
constexpr int C = 16;
constexpr int H = 512;
constexpr int W = 1024;
constexpr int HW = H * W;
constexpr int THREADS = 512;
constexpr int CG = 8;            // channels per block (2 groups)

typedef float f32x4 __attribute__((ext_vector_type(4)));

// One block per (b,h,channel-group): 512 threads, 8 channel rows in 32 KB LDS.
// vs R7 (1024 thr / 64 KB / 2 blocks/CU): now 4 blocks/CU = 4 independent
// barrier domains at the same 32 waves/CU — when one block stalls at the
// stage barrier, 3 others keep the memory pipe busy.
//   x  = clip(w + disp, 0, W-1); x0 = floor(x); x1 = min(x0+1, W-1)
//   wl = x1 - x; wr = x - x0   (both exactly 0 when x0 == W-1, so reading
//   from a = min(x0, W-2) and a+1 is always correct AND always in-bounds)
__global__ __launch_bounds__(THREADS) void warp_row_lds3(
    const float* __restrict__ input,
    const float* __restrict__ disp,
    float* __restrict__ out)
{
    __shared__ float lds[CG * W];       // 8 * 1024 * 4 B = 32 KiB

    const int blk = blockIdx.x;
    const int bh  = blk >> 1;           // b*H + h
    const int cg  = blk & 1;            // channel group (0: c0-7, 1: c8-15)
    const int b   = bh >> 9;            // H = 512
    const int h   = bh & (H - 1);
    const int t   = threadIdx.x;

    const int base0 = b * C * HW + h * W + cg * CG * HW;  // (b, cg*8, h, 0)

    // ---- Stage: 8 rows x 1024 floats = 2048 float4; 4 per thread ----
    // lds float index = f*4 (linear), f = t + i*THREADS
#pragma unroll
    for (int i = 0; i < 4; ++i) {
        const int f = t + i * THREADS;      // float4 index in [0, 2048)
        const int c = f >> 8;               // 256 float4 per channel row
        const int q = (f & 255) << 2;       // float offset within row
        const f32x4 v = *reinterpret_cast<const f32x4*>(input + base0 + c * HW + q);
        *reinterpret_cast<f32x4*>(&lds[(c << 10) + q]) = v;
    }

    // ---- Weights for this thread's two positions (overlap staging latency) ----
    const int p0 = t;
    const int p1 = t + THREADS;
    const float d0 = disp[bh * W + p0];
    const float d1 = disp[bh * W + p1];

    float x   = fminf(fmaxf((float)p0 + d0, 0.0f), (float)(W - 1));
    float x0f = floorf(x);
    const float wl0 = fminf(x0f + 1.0f, (float)(W - 1)) - x;
    const float wr0 = x - x0f;
    const int   a0  = min((int)x0f, W - 2);

    x   = fminf(fmaxf((float)p1 + d1, 0.0f), (float)(W - 1));
    x0f = floorf(x);
    const float wl1 = fminf(x0f + 1.0f, (float)(W - 1)) - x;
    const float wr1 = x - x0f;
    const int   a1  = min((int)x0f, W - 2);

    __syncthreads();

    // ---- Gather from LDS, store coalesced nontemporal ----
#pragma unroll
    for (int c = 0; c < CG; ++c) {
        const float* __restrict__ row = &lds[c << 10];
        const float o0 = wl0 * row[a0] + wr0 * row[a0 + 1];
        const float o1 = wl1 * row[a1] + wr1 * row[a1 + 1];
        float* orow = out + base0 + c * HW;
        __builtin_nontemporal_store(o0, orow + p0);
        __builtin_nontemporal_store(o1, orow + p1);
    }
}

extern "C" void kernel_launch(void* const* d_in, const int* in_sizes, int n_in,
                              void* d_out, int out_size, void* d_ws, size_t ws_size,
                              hipStream_t stream) {
    const float* input = (const float*)d_in[0];
    const float* disp  = (const float*)d_in[1];
    float* out = (float*)d_out;

    const int grid = B * H * 2;   // 8192 blocks: (b,h) x channel-group
    warp_row_lds3<<<grid, THREADS, 0, stream>>>(input, disp, out);
}